// Round 1
// baseline (300.681 us; speedup 1.0000x reference)
//
#include <hip/hip_runtime.h>
#include <stdint.h>

// Problem constants (fixed for this instance)
#define IN_C   128
#define HID_C  128
#define NREL   8
#define K_TOTAL (NREL * IN_C)   // 1024
#define TILE_M  16              // nodes per block
#define SRB     1032            // bf16 units per node row in LDS (1024 + 8 pad)

typedef float  f32x4  __attribute__((ext_vector_type(4)));
typedef __bf16 bf16x8 __attribute__((ext_vector_type(8)));
typedef short  s16x8  __attribute__((ext_vector_type(8)));
typedef unsigned short u16;

__device__ __forceinline__ unsigned short f2bf(float f) {
    unsigned int u = __float_as_uint(f);
    u += 0x7fffu + ((u >> 16) & 1u);   // round-to-nearest-even
    return (unsigned short)(u >> 16);
}

__global__ void zero_count_kernel(unsigned int* count) { *count = 0u; }

// ---------------- prep (fused): compute-node list + W->bf16 transpose
//                  + x->bf16 conversion + history copy
__global__ __launch_bounds__(256) void prep_kernel(
        const float* __restrict__ x, const float* __restrict__ W,
        const int* __restrict__ hmap, const float* __restrict__ hbuf,
        unsigned short* __restrict__ xh, unsigned short* __restrict__ Wt,
        int* __restrict__ list, unsigned int* __restrict__ count,
        float* __restrict__ out, int NN, int WE, int use_xh) {
    int gid = blockIdx.x * blockDim.x + threadIdx.x;

    // compact list of compute nodes (wave-aggregated atomics). No early
    // returns above this point: all lanes must reach the ballot.
    {
        bool active = (gid < NN) && (hmap[gid] == -1);
        unsigned long long mask = __ballot(active);
        if (mask) {
            int lane   = threadIdx.x & 63;
            int leader = __ffsll((unsigned long long)mask) - 1;
            unsigned base = 0;
            if (lane == leader) base = atomicAdd(count, (unsigned)__popcll(mask));
            base = __shfl(base, leader, 64);
            if (active) {
                int off = __popcll(mask & ((1ull << lane) - 1ull));
                list[base + off] = gid;
            }
        }
    }

    // per (node, f32x4-chunk): x -> bf16, and history-row copy
    int n = gid >> 5;           // node
    int q = gid & 31;           // f32x4 index within 128-float row
    if (n < NN) {
        if (use_xh) {
            f32x4 xv = ((const f32x4*)x)[(size_t)n * 32 + q];
            ushort4 pk;
            pk.x = f2bf(xv[0]); pk.y = f2bf(xv[1]);
            pk.z = f2bf(xv[2]); pk.w = f2bf(xv[3]);
            ((ushort4*)xh)[(size_t)n * 32 + q] = pk;   // 8 B store
        }
        if (hmap[n] != -1) {
            f32x4 v = ((const f32x4*)hbuf)[(size_t)n * 32 + q];
            f32x4* o = (f32x4*)out;
            o[(size_t)n * 32 + q] = v;
            o[(size_t)NN * 32 + (size_t)n * 32 + q] = v;
        }
    }

    // W[r][k][c] -> Wt[c][r*128+k] in bf16
    if (gid < WE) {
        int r   = gid >> 14;      // / (128*128)
        int rem = gid & 16383;
        int k   = rem >> 7;       // / 128
        int c   = rem & 127;
        Wt[(size_t)c * K_TOTAL + r * IN_C + k] = f2bf(W[gid]);
    }
}

// ---------------- fused gather (pipelined, branch-free) + bf16 MFMA GEMM
// XBF=1: gather from pre-converted bf16 x (16 B / edge / thread)
// XBF=0: fallback, gather f32 x directly (32 B / edge / thread)
template<int XBF>
__global__ __launch_bounds__(256, 4) void gemm_kernel_t(
        const float* __restrict__ x,
        const unsigned short* __restrict__ xh,
        const int* __restrict__ ptr,
        const int* __restrict__ idx,
        const int* __restrict__ ety,
        const unsigned short* __restrict__ Wt,
        const int* __restrict__ list,
        const unsigned int* __restrict__ count,
        float* __restrict__ out, int NN) {
    __shared__ u16      S[TILE_M * SRB];      // 33024 B, bf16 staged A-tile
    __shared__ unsigned meta[TILE_M * 16];    // packed src | rel<<27
    __shared__ int      nids[TILE_M];
    __shared__ int      degs[TILE_M];
    __shared__ float    invdeg[TILE_M];

    unsigned int cnt = *count;
    int rowbase = blockIdx.x * TILE_M;
    if (rowbase >= (int)cnt) return;          // uniform exit, before any barrier

    int t = threadIdx.x;
    if (t < TILE_M) {
        int row = rowbase + t;
        int nid = -1, d = 0; float idg = 0.f;
        if (row < (int)cnt) {
            nid = list[row];
            int e0 = ptr[nid], e1 = ptr[nid + 1];
            d = e1 - e0;
            idg = (d > 0) ? 1.0f / (float)d : 0.f;
        }
        nids[t] = nid; degs[t] = d; invdeg[t] = idg;
    }
    __syncthreads();

    int n = t >> 4;            // node slot 0..15
    int c = t & 15;            // 8-channel chunk 0..15
    int nid = nids[n];
    int deg = degs[n];
    int e0  = (nid >= 0) ? ptr[nid] : 0;

    int maxdeg = 0;
    #pragma unroll
    for (int i = 0; i < TILE_M; ++i) maxdeg = max(maxdeg, degs[i]);

    // per-thread accumulator: 8 relations x 8 channels (64 VGPRs)
    f32x4 alo[NREL], ahi[NREL];
    #pragma unroll
    for (int r = 0; r < NREL; ++r) { alo[r] = f32x4{0,0,0,0}; ahi[r] = f32x4{0,0,0,0}; }

    // byte base of this thread's channel chunk
    const char* xcb = XBF ? ((const char*)xh + c * 16)
                          : ((const char*)x  + c * 32);

    // accumulate one bf16 edge-chunk (8 channels) into the one-hot buckets
    auto accum_bf = [&](uint4 v, unsigned m) {
        int r_ = (int)(m >> 27);
        f32x4 lo_, hi_;
        lo_[0] = __uint_as_float(v.x << 16);
        lo_[1] = __uint_as_float(v.x & 0xFFFF0000u);
        lo_[2] = __uint_as_float(v.y << 16);
        lo_[3] = __uint_as_float(v.y & 0xFFFF0000u);
        hi_[0] = __uint_as_float(v.z << 16);
        hi_[1] = __uint_as_float(v.z & 0xFFFF0000u);
        hi_[2] = __uint_as_float(v.w << 16);
        hi_[3] = __uint_as_float(v.w & 0xFFFF0000u);
        #pragma unroll
        for (int rr = 0; rr < NREL; ++rr) {       // branchless one-hot
            float mk = (r_ == rr) ? 1.0f : 0.0f;
            alo[rr] += lo_ * mk;
            ahi[rr] += hi_ * mk;
        }
    };
    auto accum_f32 = [&](f32x4 lo_, f32x4 hi_, unsigned m) {
        int r_ = (int)(m >> 27);
        #pragma unroll
        for (int rr = 0; rr < NREL; ++rr) {
            float mk = (r_ == rr) ? 1.0f : 0.0f;
            alo[rr] += lo_ * mk;
            ahi[rr] += hi_ * mk;
        }
    };

    for (int jb = 0; jb < maxdeg; jb += 16) {
        // stage this 16-edge chunk's meta, coalesced.  Invalid edges get
        // src=0, rel=31 (one-hot never matches, load stays in-bounds).
        {
            int j = jb + c;
            unsigned m = 31u << 27;
            if (nid >= 0 && j < deg) {
                int e = e0 + j;
                m = ((unsigned)idx[e]) | (((unsigned)ety[e]) << 27);
            }
            meta[t] = m;
        }
        __syncthreads();

        // pull all 16 metas into registers (4 x ds_read_b128, broadcast)
        unsigned mm[16];
        {
            uint4 q0 = *(const uint4*)(meta + (n << 4) + 0);
            uint4 q1 = *(const uint4*)(meta + (n << 4) + 4);
            uint4 q2 = *(const uint4*)(meta + (n << 4) + 8);
            uint4 q3 = *(const uint4*)(meta + (n << 4) + 12);
            mm[0]=q0.x;  mm[1]=q0.y;  mm[2]=q0.z;  mm[3]=q0.w;
            mm[4]=q1.x;  mm[5]=q1.y;  mm[6]=q1.z;  mm[7]=q1.w;
            mm[8]=q2.x;  mm[9]=q2.y;  mm[10]=q2.z; mm[11]=q2.w;
            mm[12]=q3.x; mm[13]=q3.y; mm[14]=q3.z; mm[15]=q3.w;
        }

        if (XBF) {
            // bf16 path: one dwordx4 per edge; 4-edge batches, double-buffered
            uint4 cur[4];
            #pragma unroll
            for (int u = 0; u < 4; ++u)
                cur[u] = *(const uint4*)(xcb + ((size_t)(mm[u] & 0x07FFFFFFu) << 8));
            #pragma unroll
            for (int b = 0; b < 4; ++b) {
                uint4 nxt[4];
                if (b < 3) {
                    #pragma unroll
                    for (int u = 0; u < 4; ++u)
                        nxt[u] = *(const uint4*)(xcb + ((size_t)(mm[(b+1)*4+u] & 0x07FFFFFFu) << 8));
                }
                #pragma unroll
                for (int u = 0; u < 4; ++u) accum_bf(cur[u], mm[b*4+u]);
                if (b < 3) {
                    #pragma unroll
                    for (int u = 0; u < 4; ++u) cur[u] = nxt[u];
                }
            }
        } else {
            // f32 fallback: two dwordx4 per edge
            f32x4 clo[4], chi[4];
            #pragma unroll
            for (int u = 0; u < 4; ++u) {
                const f32x4* p = (const f32x4*)(xcb + ((size_t)(mm[u] & 0x07FFFFFFu) << 9));
                clo[u] = p[0]; chi[u] = p[1];
            }
            #pragma unroll
            for (int b = 0; b < 4; ++b) {
                f32x4 nlo[4], nhi[4];
                if (b < 3) {
                    #pragma unroll
                    for (int u = 0; u < 4; ++u) {
                        const f32x4* p = (const f32x4*)(xcb + ((size_t)(mm[(b+1)*4+u] & 0x07FFFFFFu) << 9));
                        nlo[u] = p[0]; nhi[u] = p[1];
                    }
                }
                #pragma unroll
                for (int u = 0; u < 4; ++u) accum_f32(clo[u], chi[u], mm[b*4+u]);
                if (b < 3) {
                    #pragma unroll
                    for (int u = 0; u < 4; ++u) { clo[u] = nlo[u]; chi[u] = nhi[u]; }
                }
            }
        }
        __syncthreads();   // meta reuse fence for next chunk
    }

    // convert once to bf16, write S tile (write-once, no zeroing needed)
    {
        u16* srow = S + n * SRB + c * 8;
        #pragma unroll
        for (int rr = 0; rr < NREL; ++rr) {
            s16x8 pk;
            pk[0] = (short)f2bf(alo[rr][0]); pk[1] = (short)f2bf(alo[rr][1]);
            pk[2] = (short)f2bf(alo[rr][2]); pk[3] = (short)f2bf(alo[rr][3]);
            pk[4] = (short)f2bf(ahi[rr][0]); pk[5] = (short)f2bf(ahi[rr][1]);
            pk[6] = (short)f2bf(ahi[rr][2]); pk[7] = (short)f2bf(ahi[rr][3]);
            *(s16x8*)(srow + rr * IN_C) = pk;
        }
    }
    __syncthreads();

    // MFMA over K=1024
    int wave = t >> 6, lane = t & 63;
    int quad = lane >> 4, l16 = lane & 15;
    int chbase = wave * 32;                 // each wave owns 32 output channels
    const u16* arow  = S + l16 * SRB + quad * 8;
    const u16* bbase = Wt + (size_t)(chbase + l16) * K_TOTAL + quad * 8;

    f32x4 acc0 = {0.f,0.f,0.f,0.f};
    f32x4 acc1 = {0.f,0.f,0.f,0.f};
    #pragma unroll 8
    for (int ks = 0; ks < K_TOTAL; ks += 32) {
        s16x8 a  = *(const s16x8*)(arow + ks);
        s16x8 b0 = *(const s16x8*)(bbase + ks);
        s16x8 b1 = *(const s16x8*)(bbase + ks + 16 * K_TOTAL);
        union { s16x8 s; bf16x8 b; } ua, ub0, ub1;
        ua.s = a; ub0.s = b0; ub1.s = b1;
        acc0 = __builtin_amdgcn_mfma_f32_16x16x32_bf16(ua.b, ub0.b, acc0, 0, 0, 0);
        acc1 = __builtin_amdgcn_mfma_f32_16x16x32_bf16(ua.b, ub1.b, acc1, 0, 0, 0);
    }

    // epilogue: C/D layout col=lane&15, row=(lane>>4)*4+reg
    size_t half = (size_t)NN * HID_C;
    #pragma unroll
    for (int v = 0; v < 4; ++v) {
        int rowl = quad * 4 + v;
        int onid = nids[rowl];
        if (onid < 0) continue;
        float s = invdeg[rowl];
        float v0 = acc0[v] * s;
        float v1 = acc1[v] * s;
        size_t o0 = (size_t)onid * HID_C + chbase + l16;
        out[o0]             = v0;
        out[o0 + 16]        = v1;
        out[o0 + half]      = v0;
        out[o0 + 16 + half] = v1;
    }
}

extern "C" void kernel_launch(void* const* d_in, const int* in_sizes, int n_in,
                              void* d_out, int out_size, void* d_ws, size_t ws_size,
                              hipStream_t stream) {
    const float* x    = (const float*)d_in[0];
    const float* W    = (const float*)d_in[1];
    const int*   ptr  = (const int*)d_in[2];
    const int*   idx  = (const int*)d_in[3];
    const int*   ety  = (const int*)d_in[4];
    const int*   hmap = (const int*)d_in[5];
    const float* hbuf = (const float*)d_in[6];
    int NN = in_sizes[5];          // 100000
    int WE = in_sizes[1];          // 8*128*128
    float* out = (float*)d_out;

    // workspace layout: count | list | Wt(bf16) | xh(bf16 x)
    unsigned int* count = (unsigned int*)d_ws;
    int* list = (int*)((char*)d_ws + 256);
    size_t wt_off = 256 + (((size_t)NN * 4 + 4095) / 4096) * 4096;
    unsigned short* Wt = (unsigned short*)((char*)d_ws + wt_off);      // 256 KB
    size_t xh_off = ((wt_off + (size_t)K_TOTAL * HID_C * 2 + 4095) / 4096) * 4096;
    unsigned short* xh = (unsigned short*)((char*)d_ws + xh_off);      // NN*128*2 B
    size_t need = xh_off + (size_t)NN * IN_C * 2;
    int use_xh = (ws_size >= need) ? 1 : 0;

    zero_count_kernel<<<1, 1, 0, stream>>>(count);

    long long tot = (long long)NN * 32;           // covers x-conv + history
    if (tot < (long long)WE) tot = WE;
    prep_kernel<<<(int)((tot + 255) / 256), 256, 0, stream>>>(
        x, W, hmap, hbuf, xh, Wt, list, count, out, NN, WE, use_xh);

    int gblocks = (NN + TILE_M - 1) / TILE_M;
    if (use_xh) {
        gemm_kernel_t<1><<<gblocks, 256, 0, stream>>>(
            x, xh, ptr, idx, ety, Wt, list, count, out, NN);
    } else {
        gemm_kernel_t<0><<<gblocks, 256, 0, stream>>>(
            x, xh, ptr, idx, ety, Wt, list, count, out, NN);
    }
}